// Round 14
// baseline (342.319 us; speedup 1.0000x reference)
//
#include <hip/hip_runtime.h>
#include <hip/hip_bf16.h>
#include <math.h>

#define N_PTS 8192
#define M_PTS 2048
#define KLAST 10
#define VARS 3
#define OUTD 32
#define D1 80
#define D2 80
#define PB 16         // points per agg block
#define LPTS 8        // output points per last block (256 blocks, 1/CU)
#define NT 768        // 12 waves
#define NWAVES 12
#define TPCH 104      // Tb row pitch in bf16 (208 B; stride-52 dwords -> 2-way banks)
#define W0P 72        // W0 K-pitch (K=64 used: feats 0..32, pos 32..36, pad ..64)
#define W1P 104       // W1/W2 K-pitch (K=80 padded to 96)
#define RP 40         // f0b/f1b record pitch in bf16 (80 B: [32 feats | ypos | pad])

typedef float f4 __attribute__((ext_vector_type(4)));
typedef short bf16x8 __attribute__((ext_vector_type(8)));

// lean inf-safe tanh-gelu: gelu = x - x*rcp(exp2(x*(A+B*x^2))+1); err ~3e-4.
__device__ __forceinline__ float gelu_f(float x) {
    float x2 = x * x;
    float s = x * __builtin_fmaf(0.1029418f, x2, 2.3022083f);
    float u = __builtin_amdgcn_exp2f(s);
    float r = __builtin_amdgcn_rcpf(u + 1.0f);
    return __builtin_fmaf(-x, r, x);
}
__device__ __forceinline__ unsigned short f2bf(float x) {
    unsigned int u = __float_as_uint(x);
    u += 0x7FFF + ((u >> 16) & 1);
    return (unsigned short)(u >> 16);
}
__device__ __forceinline__ float bf2f(unsigned short h) {
    return __uint_as_float(((unsigned int)h) << 16);
}
// packed RNE f32x2 -> bf16x2 (v_cvt_pk_bf16_f32 on gfx950)
__device__ __forceinline__ int pk2(float a, float b) {
    __hip_bfloat162 h = __float22bfloat162_rn(float2{a, b});
    int r; __builtin_memcpy(&r, &h, 4); return r;
}

// Stage single-bf16 weights transposed [col][k], K zero-padded.
// W0 k-order REORDERED to record layout: k 0..31 <- W0g rows 4..35 (features),
// k 32..35 <- W0g rows 0..3 (pos), rest 0.
__device__ __forceinline__ void stage_weights(
    unsigned short* W0h, unsigned short* W1h, unsigned short* W2h, float* bs,
    const float* __restrict__ W0g, const float* __restrict__ b0g,
    const float* __restrict__ W1g, const float* __restrict__ b1g,
    const float* __restrict__ W2g, const float* __restrict__ b2g, int t)
{
    for (int idx = t; idx < D1 * W0P; idx += NT) {
        int col = idx / W0P, k = idx - col * W0P;
        float w = (k < 32) ? W0g[(k + 4) * D1 + col]
                           : ((k < 36) ? W0g[(k - 32) * D1 + col] : 0.0f);
        W0h[idx] = f2bf(w);
    }
    for (int idx = t; idx < D1 * W1P; idx += NT) {
        int col = idx / W1P, k = idx - col * W1P;
        W1h[idx] = f2bf((k < D2) ? W1g[k * D1 + col] : 0.0f);
    }
    for (int idx = t; idx < OUTD * W1P; idx += NT) {
        int col = idx / W1P, k = idx - col * W1P;
        W2h[idx] = f2bf((k < D2) ? W2g[k * OUTD + col] : 0.0f);
    }
    for (int idx = t; idx < 192; idx += NT)
        bs[idx] = (idx < 80) ? b0g[idx] : (idx < 160 ? b1g[idx - 80] : b2g[idx - 160]);
}

// Per-wave 16-row chunk MLP (R12 structure + weight-frag ROTATION).
// Rotation: cb+1's weight ds_reads are issued at the top of iteration cb and
// consumed next iteration — lgkm ops retire in order, so the wait for the
// prefetched frags lands after the MFMA+gelu+store body and the ds_read
// latency is hidden. Costs only the rotation registers (+8..12 VGPRs, die at
// loop end). cb loops stay unroll-1 ON PURPOSE — every widened-live-set
// attempt (full unroll R2/R3, VGPR w2f R6/R7, unroll-2+6-frag R9) spilled to
// scratch under the reg cap. Spill tripwire: FETCH/WRITE counters.
__device__ __forceinline__ void mlp_chunk(
    int4 featsi, int4 posfi, unsigned short* Trow,
    const unsigned short* W0h, const unsigned short* W1h,
    const unsigned short* W2h, const float* bs, int lm, int quad)
{
    bf16x8 b1f0 = *(bf16x8*)&featsi;
    bf16x8 b1f1 = *(bf16x8*)&posfi;
    // ---- L1: K=64 (feats+pos+pad) -> 80, gelu ----
    {
        const unsigned short* w0 = &W0h[lm * W0P + quad * 8];
        bf16x8 a0 = *(const bf16x8*)&w0[0];
        bf16x8 a1 = *(const bf16x8*)&w0[32];
#pragma unroll 1
        for (int cb = 0; cb < 5; ++cb) {
            int nx = (cb < 4) ? (cb + 1) : 4;
            const unsigned short* wn = &W0h[(nx * 16 + lm) * W0P + quad * 8];
            bf16x8 n0 = *(const bf16x8*)&wn[0];
            bf16x8 n1 = *(const bf16x8*)&wn[32];
            f4 acc = *(const f4*)&bs[cb * 16 + quad * 4];
            acc = __builtin_amdgcn_mfma_f32_16x16x32_bf16(a0, b1f0, acc, 0, 0, 0);
            acc = __builtin_amdgcn_mfma_f32_16x16x32_bf16(a1, b1f1, acc, 0, 0, 0);
            *(int2*)&Trow[cb * 16 + quad * 4] =
                make_int2(pk2(gelu_f(acc.x), gelu_f(acc.y)),
                          pk2(gelu_f(acc.z), gelu_f(acc.w)));
            a0 = n0; a1 = n1;
        }
    }
    // ---- L2: 80(pad 96) -> 80, gelu ----
    bf16x8 b2f[3];
    b2f[0] = *(const bf16x8*)&Trow[quad * 8];
    b2f[1] = *(const bf16x8*)&Trow[32 + quad * 8];
    b2f[2] = *(const bf16x8*)&Trow[64 + quad * 8];
    {
        const unsigned short* w1 = &W1h[lm * W1P + quad * 8];
        bf16x8 h0 = *(const bf16x8*)&w1[0];
        bf16x8 h1 = *(const bf16x8*)&w1[32];
        bf16x8 h2 = *(const bf16x8*)&w1[64];
#pragma unroll 1
        for (int cb = 0; cb < 5; ++cb) {
            int nx = (cb < 4) ? (cb + 1) : 4;
            const unsigned short* wn = &W1h[(nx * 16 + lm) * W1P + quad * 8];
            bf16x8 n0 = *(const bf16x8*)&wn[0];
            bf16x8 n1 = *(const bf16x8*)&wn[32];
            bf16x8 n2 = *(const bf16x8*)&wn[64];
            f4 acc = *(const f4*)&bs[80 + cb * 16 + quad * 4];
            acc = __builtin_amdgcn_mfma_f32_16x16x32_bf16(h0, b2f[0], acc, 0, 0, 0);
            acc = __builtin_amdgcn_mfma_f32_16x16x32_bf16(h1, b2f[1], acc, 0, 0, 0);
            acc = __builtin_amdgcn_mfma_f32_16x16x32_bf16(h2, b2f[2], acc, 0, 0, 0);
            *(int2*)&Trow[cb * 16 + quad * 4] =
                make_int2(pk2(gelu_f(acc.x), gelu_f(acc.y)),
                          pk2(gelu_f(acc.z), gelu_f(acc.w)));
            h0 = n0; h1 = n1; h2 = n2;
        }
    }
    // ---- L3: 80(pad 96) -> 32, fp32 out at Trow floats [0..32) ----
    bf16x8 b3f[3];
    b3f[0] = *(const bf16x8*)&Trow[quad * 8];
    b3f[1] = *(const bf16x8*)&Trow[32 + quad * 8];
    b3f[2] = *(const bf16x8*)&Trow[64 + quad * 8];
    float* po = (float*)Trow;
    {
        const unsigned short* w2 = &W2h[lm * W1P + quad * 8];
        bf16x8 h0 = *(const bf16x8*)&w2[0];
        bf16x8 h1 = *(const bf16x8*)&w2[32];
        bf16x8 h2 = *(const bf16x8*)&w2[64];
#pragma unroll 1
        for (int cb = 0; cb < 2; ++cb) {
            const unsigned short* wn = &W2h[(16 + lm) * W1P + quad * 8];
            bf16x8 n0 = *(const bf16x8*)&wn[0];
            bf16x8 n1 = *(const bf16x8*)&wn[32];
            bf16x8 n2 = *(const bf16x8*)&wn[64];
            f4 acc = *(const f4*)&bs[160 + cb * 16 + quad * 4];
            acc = __builtin_amdgcn_mfma_f32_16x16x32_bf16(h0, b3f[0], acc, 0, 0, 0);
            acc = __builtin_amdgcn_mfma_f32_16x16x32_bf16(h1, b3f[1], acc, 0, 0, 0);
            acc = __builtin_amdgcn_mfma_f32_16x16x32_bf16(h2, b3f[2], acc, 0, 0, 0);
            *(f4*)&po[cb * 16 + quad * 4] = acc;
            h0 = n0; h1 = n1; h2 = n2;
        }
    }
}

// ---- merged projection + scan: blocks 0..767 proj, block 768 scans counts ----
__global__ __launch_bounds__(256) void proj_scan_kernel(
    const float* __restrict__ inp, const float* __restrict__ grid_in,
    const float* __restrict__ W0, const float* __restrict__ b0,
    const float* __restrict__ W1, const float* __restrict__ b1,
    unsigned short* __restrict__ f0b,
    const int* __restrict__ counts, int* __restrict__ offsets)
{
    const int t = threadIdx.x;
    if (blockIdx.x == 768) {
        __shared__ int ws2[4], wx2[4];
        const int lane = t & 63, wave = t >> 6;
        int4 a[8];
#pragma unroll
        for (int i = 0; i < 8; ++i) a[i] = ((const int4*)counts)[t * 8 + i];
        int s = 0;
#pragma unroll
        for (int i = 0; i < 8; ++i) s += a[i].x + a[i].y + a[i].z + a[i].w;
        int x = s;
#pragma unroll
        for (int d = 1; d < 64; d <<= 1) {
            int y = __shfl_up(x, d);
            if (lane >= d) x += y;
        }
        if (lane == 63) ws2[wave] = x;
        __syncthreads();
        if (t == 0) {
            wx2[0] = 0;
            wx2[1] = ws2[0];
            wx2[2] = ws2[0] + ws2[1];
            wx2[3] = ws2[0] + ws2[1] + ws2[2];
        }
        __syncthreads();
        int base = wx2[wave] + (x - s);
#pragma unroll
        for (int i = 0; i < 8; ++i) {
            int4 c = a[i];
            int4 o;
            o.x = base; base += c.x;
            o.y = base; base += c.y;
            o.z = base; base += c.z;
            o.w = base; base += c.w;
            ((int4*)offsets)[t * 8 + i] = o;
        }
        return;
    }
    __shared__ float W0s[8 * 64];
    __shared__ float W1s[64 * OUTD];
    __shared__ float xs[32 * 8];
    __shared__ float H[32 * 64];
    const int r0 = blockIdx.x * 32;
    for (int idx = t; idx < 512; idx += 256) W0s[idx] = W0[idx];
    for (int idx = t; idx < 64 * OUTD; idx += 256) W1s[idx] = W1[idx];
    xs[t] = inp[r0 * 8 + t];
    if (t < 32) {
        int row = r0 + t, n = row / 3, v = row - n * 3;
        *(int*)(f0b + ((size_t)(v << 13) + n) * RP + 32) =
            pk2(grid_in[2 * n], grid_in[2 * n + 1]);
    }
    __syncthreads();
#pragma unroll 1
    for (int p = 0; p < 8; ++p) {
        int o = t + 256 * p, r = o >> 6, col = o & 63;
        float s = b0[col];
#pragma unroll
        for (int k = 0; k < 8; ++k) s += xs[r * 8 + k] * W0s[k * 64 + col];
        H[o] = gelu_f(s);
    }
    __syncthreads();
#pragma unroll 1
    for (int p = 0; p < 4; ++p) {
        int o = t + 256 * p, r = o >> 5, c = o & 31;
        float s = b1[c];
#pragma unroll 8
        for (int k = 0; k < 64; ++k) s += H[r * 64 + k] * W1s[k * OUTD + c];
        int row = r0 + r;
        int n = row / 3, v = row - n * 3;
        f0b[((size_t)(v << 13) + n) * RP + c] = f2bf(s);
    }
}

// ---- edge MLP + owner-computes segment mean (R12 structure) ----
// 12 waves x 768 thr; LDS 81,920 B -> 2 blocks/CU (24 waves/CU).
__global__ __launch_bounds__(768, 6) void agg_kernel(
    const float* __restrict__ grid_in, const unsigned short* __restrict__ f0b,
    const int* __restrict__ nbr_index, const int* __restrict__ offsets,
    const int* __restrict__ counts,
    const float* __restrict__ W0g, const float* __restrict__ b0g,
    const float* __restrict__ W1g, const float* __restrict__ b1g,
    const float* __restrict__ W2g, const float* __restrict__ b2g,
    unsigned short* __restrict__ f1b)
{
    __shared__ __attribute__((aligned(16))) unsigned short Tb[NWAVES * 16 * TPCH];
    __shared__ __attribute__((aligned(16))) unsigned short W0h[D1 * W0P];
    __shared__ __attribute__((aligned(16))) unsigned short W1h[D1 * W1P];
    __shared__ __attribute__((aligned(16))) unsigned short W2h[OUTD * W1P];
    __shared__ __attribute__((aligned(16))) float bs[192];
    __shared__ __attribute__((aligned(16))) float accH[VARS * PB * 32];
    __shared__ int offs[PB + 1];
    __shared__ int px2b[PB];
    __shared__ float invb[PB];

    const int t = threadIdx.x;
    const int lane = t & 63, wave = t >> 6;
    const int lm = lane & 15, quad = lane >> 4;
    const int p0 = blockIdx.x * PB;

    stage_weights(W0h, W1h, W2h, bs, W0g, b0g, W1g, b1g, W2g, b2g, t);
    if (t < PB) {
        offs[t] = offsets[p0 + t];
        int c = counts[p0 + t];
        invb[t] = 1.0f / (float)(c > 1 ? c : 1);
        px2b[t] = pk2(grid_in[2 * (p0 + t)], grid_in[2 * (p0 + t) + 1]);
    }
    if (t == PB) offs[PB] = offsets[p0 + PB - 1] + counts[p0 + PB - 1];
    for (int idx = t; idx < VARS * PB * 32; idx += NT) accH[idx] = 0.0f;
    __syncthreads();

    // zero persistent pad [80..96) of this wave's 16 rows (never rewritten)
    unsigned short* TbW = Tb + (wave * 16) * TPCH;
    if (lane < 32)
        *(int4*)(TbW + (lane >> 1) * TPCH + 80 + (lane & 1) * 8) = make_int4(0, 0, 0, 0);

    const int e0 = offs[0];
    const int cntT = offs[PB] - e0;
    const int Rb = VARS * cntT;
    const int nch = (Rb + 15) >> 4;

    unsigned short* Trow = TbW + lm * TPCH;

    // prefetch state for chunk ch
    int pkey; int4 pfeats, pposf;
    {
        int myrow = (wave << 4) + lm;
        pkey = -1; pfeats = make_int4(0,0,0,0); pposf = make_int4(0,0,0,0);
        if (myrow < Rb) {
            int myv = (myrow >= 2 * cntT) ? 2 : ((myrow >= cntT) ? 1 : 0);
            int e = e0 + myrow - myv * cntT;
            int myj = nbr_index[e];
            int lp = 0;
#pragma unroll
            for (int l = 1; l < PB; ++l) lp += (e >= offs[l]);
            pkey = myv * PB + lp;
            const unsigned short* rec = f0b + ((size_t)(myv << 13) + myj) * RP;
            pfeats = ((const int4*)rec)[quad];
            if (quad == 0) pposf = make_int4(*(const int*)(rec + 32), px2b[lp], 0, 0);
        }
    }

    for (int ch = wave; ch < nch; ch += NWAVES) {
        int ckey = pkey; int4 cfeats = pfeats, cposf = pposf;
        // issue next chunk's gather before the MLP (latency hides behind MFMA)
        int nc = ch + NWAVES;
        pkey = -1; pfeats = make_int4(0,0,0,0); pposf = make_int4(0,0,0,0);
        if (nc < nch) {
            int myrow = (nc << 4) + lm;
            if (myrow < Rb) {
                int myv = (myrow >= 2 * cntT) ? 2 : ((myrow >= cntT) ? 1 : 0);
                int e = e0 + myrow - myv * cntT;
                int myj = nbr_index[e];
                int lp = 0;
#pragma unroll
                for (int l = 1; l < PB; ++l) lp += (e >= offs[l]);
                pkey = myv * PB + lp;
                const unsigned short* rec = f0b + ((size_t)(myv << 13) + myj) * RP;
                pfeats = ((const int4*)rec)[quad];
                if (quad == 0) pposf = make_int4(*(const int*)(rec + 32), px2b[lp], 0, 0);
            }
        }
        if (ckey < 0) { cfeats = make_int4(0,0,0,0); cposf = make_int4(0,0,0,0); }
        mlp_chunk(cfeats, cposf, Trow, W0h, W1h, W2h, bs, lm, quad);
        // keyed reduction of this wave's 16 rows into block accumulator
        int col = lane & 31, eo = lane >> 5;
#pragma unroll 1
        for (int e2 = eo; e2 < 16; e2 += 2) {
            int k = __shfl(ckey, e2);
            if (k >= 0)
                atomicAdd(&accH[k * 32 + col], ((const float*)(TbW + e2 * TPCH))[col]);
        }
    }
    __syncthreads();
    for (int idx = t; idx < VARS * PB * OUTD; idx += NT) {
        int key = idx >> 5, c = idx & 31;
        int v = key >> 4, lp = key & 15;
        size_t rec = ((size_t)(v << 13) + p0 + lp) * RP;
        float val = accH[key * 32 + c] * invb[lp] + bf2f(f0b[rec + c]);
        f1b[rec + c] = f2bf(val);
    }
    if (t < VARS * PB) {
        int v = t >> 4, lp = t & 15;
        *(int*)(f1b + ((size_t)(v << 13) + p0 + lp) * RP + 32) = px2b[lp];
    }
}

// ---- kNN MLP + mean over K ----
__global__ __launch_bounds__(768, 6) void last_kernel(
    const unsigned short* __restrict__ f1b, const float* __restrict__ grid_out,
    const int* __restrict__ nbr_last,
    const float* __restrict__ W0g, const float* __restrict__ b0g,
    const float* __restrict__ W1g, const float* __restrict__ b1g,
    const float* __restrict__ W2g, const float* __restrict__ b2g,
    float* __restrict__ out)
{
    __shared__ __attribute__((aligned(16))) unsigned short Tb[NWAVES * 16 * TPCH];
    __shared__ __attribute__((aligned(16))) unsigned short W0h[D1 * W0P];
    __shared__ __attribute__((aligned(16))) unsigned short W1h[D1 * W1P];
    __shared__ __attribute__((aligned(16))) unsigned short W2h[OUTD * W1P];
    __shared__ __attribute__((aligned(16))) float bs[192];
    __shared__ __attribute__((aligned(16))) float accH[LPTS * VARS * 32];
    __shared__ int pxo2b[LPTS];

    const int t = threadIdx.x;
    const int lane = t & 63, wave = t >> 6;
    const int lm = lane & 15, quad = lane >> 4;
    const int m0 = blockIdx.x * LPTS;

    stage_weights(W0h, W1h, W2h, bs, W0g, b0g, W1g, b1g, W2g, b2g, t);
    if (t < LPTS)
        pxo2b[t] = pk2(grid_out[2 * (m0 + t)], grid_out[2 * (m0 + t) + 1]);
    for (int idx = t; idx < LPTS * VARS * 32; idx += NT) accH[idx] = 0.0f;
    __syncthreads();
    unsigned short* TbW = Tb + (wave * 16) * TPCH;
    if (lane < 32)
        *(int4*)(TbW + (lane >> 1) * TPCH + 80 + (lane & 1) * 8) = make_int4(0, 0, 0, 0);

    const int Rb = LPTS * VARS * KLAST;   // 240
    const int nch = (Rb + 15) >> 4;       // 15
    unsigned short* Trow = TbW + lm * TPCH;

    for (int ch = wave; ch < nch; ch += NWAVES) {
        int myrow = (ch << 4) + lm;
        int ckey = -1; int4 cfeats = make_int4(0,0,0,0), cposf = make_int4(0,0,0,0);
        if (myrow < Rb) {
            int lp = myrow / 30, rr = myrow - lp * 30;
            int v = rr / KLAST, kk = rr - v * KLAST;
            int myj = nbr_last[(m0 + lp) * KLAST + kk];
            ckey = lp * VARS + v;
            const unsigned short* rec = f1b + ((size_t)(v << 13) + myj) * RP;
            cfeats = ((const int4*)rec)[quad];
            if (quad == 0) cposf = make_int4(*(const int*)(rec + 32), pxo2b[lp], 0, 0);
        }
        mlp_chunk(cfeats, cposf, Trow, W0h, W1h, W2h, bs, lm, quad);
        int col = lane & 31, eo = lane >> 5;
#pragma unroll 1
        for (int e2 = eo; e2 < 16; e2 += 2) {
            int k = __shfl(ckey, e2);
            if (k >= 0)
                atomicAdd(&accH[k * 32 + col], ((const float*)(TbW + e2 * TPCH))[col]);
        }
    }
    __syncthreads();
    if (t < LPTS * VARS * OUTD) {
        int key = t >> 5, c = t & 31;
        int lp = key / VARS, v = key - lp * VARS;
        out[((size_t)(m0 + lp) * VARS + v) * OUTD + c] = accH[key * 32 + c] * (1.0f / KLAST);
    }
}

extern "C" void kernel_launch(void* const* d_in, const int* in_sizes, int n_in,
                              void* d_out, int out_size, void* d_ws, size_t ws_size,
                              hipStream_t stream) {
    const float* inp      = (const float*)d_in[0];
    const float* grid_in  = (const float*)d_in[1];
    const float* grid_out = (const float*)d_in[2];
    const float* pW0 = (const float*)d_in[3];
    const float* pb0 = (const float*)d_in[4];
    const float* pW1 = (const float*)d_in[5];
    const float* pb1 = (const float*)d_in[6];
    const float* i0W0 = (const float*)d_in[7];
    const float* i0b0 = (const float*)d_in[8];
    const float* i0W1 = (const float*)d_in[9];
    const float* i0b1 = (const float*)d_in[10];
    const float* i0W2 = (const float*)d_in[11];
    const float* i0b2 = (const float*)d_in[12];
    const float* i1W0 = (const float*)d_in[13];
    const float* i1b0 = (const float*)d_in[14];
    const float* i1W1 = (const float*)d_in[15];
    const float* i1b1 = (const float*)d_in[16];
    const float* i1W2 = (const float*)d_in[17];
    const float* i1b2 = (const float*)d_in[18];
    const int* nbr_index  = (const int*)d_in[19];
    const int* nbr_counts = (const int*)d_in[21];
    const int* nbr_last   = (const int*)d_in[22];

    unsigned short* f0b = (unsigned short*)d_ws;                      // 3*8192*40 bf16
    unsigned short* f1b = f0b + (size_t)VARS * N_PTS * RP;            // 3*8192*40 bf16
    int* offsets = (int*)(f1b + (size_t)VARS * N_PTS * RP);           // N

    proj_scan_kernel<<<769, 256, 0, stream>>>(inp, grid_in, pW0, pb0, pW1, pb1,
                                              f0b, nbr_counts, offsets);
    agg_kernel<<<N_PTS / PB, NT, 0, stream>>>(grid_in, f0b, nbr_index, offsets,
                                              nbr_counts,
                                              i0W0, i0b0, i0W1, i0b1, i0W2, i0b2, f1b);
    last_kernel<<<M_PTS / LPTS, NT, 0, stream>>>(f1b, grid_out, nbr_last,
                                                 i1W0, i1b0, i1W1, i1b1, i1W2, i1b2,
                                                 (float*)d_out);
}

// Round 15
// 320.626 us; speedup vs baseline: 1.0677x; 1.0677x over previous
//
#include <hip/hip_runtime.h>
#include <hip/hip_bf16.h>
#include <math.h>

#define N_PTS 8192
#define M_PTS 2048
#define KLAST 10
#define VARS 3
#define OUTD 32
#define D1 80
#define D2 80
#define PB 16         // points per agg block
#define LPTS 8        // output points per last block (256 blocks, 1/CU)
#define NT 768        // 12 waves
#define NWAVES 12
#define TPCH 104      // Tb row pitch in bf16 (208 B; stride-52 dwords -> 2-way banks)
#define W0P 72        // W0 K-pitch (K=64 used: feats 0..32, pos 32..36, pad ..64)
#define W1P 104       // W1/W2 K-pitch (K=80 padded to 96)
#define RP 40         // f0b/f1b record pitch in bf16 (80 B: [32 feats | ypos | pad])
#define W0SZ (D1 * W0P)              // 5760
#define W1SZ (D1 * W1P)              // 8320
#define W2SZ (OUTD * W1P)            // 3328
#define WPACK (W0SZ + W1SZ + W2SZ)   // 17408 bf16 elems per weight set

typedef float f4 __attribute__((ext_vector_type(4)));
typedef short bf16x8 __attribute__((ext_vector_type(8)));

// lean inf-safe tanh-gelu: gelu = x - x*rcp(exp2(x*(A+B*x^2))+1); err ~3e-4.
__device__ __forceinline__ float gelu_f(float x) {
    float x2 = x * x;
    float s = x * __builtin_fmaf(0.1029418f, x2, 2.3022083f);
    float u = __builtin_amdgcn_exp2f(s);
    float r = __builtin_amdgcn_rcpf(u + 1.0f);
    return __builtin_fmaf(-x, r, x);
}
__device__ __forceinline__ unsigned short f2bf(float x) {
    unsigned int u = __float_as_uint(x);
    u += 0x7FFF + ((u >> 16) & 1);
    return (unsigned short)(u >> 16);
}
__device__ __forceinline__ float bf2f(unsigned short h) {
    return __uint_as_float(((unsigned int)h) << 16);
}
// packed RNE f32x2 -> bf16x2 (v_cvt_pk_bf16_f32 on gfx950)
__device__ __forceinline__ int pk2(float a, float b) {
    __hip_bfloat162 h = __float22bfloat162_rn(float2{a, b});
    int r; __builtin_memcpy(&r, &h, 4); return r;
}

// One-time pack: single-bf16 weights transposed [col][k], K zero-padded, in
// the exact layout agg/last stage into LDS. W0 k-order REORDERED to record
// layout: k 0..31 <- W0g rows 4..35 (features), k 32..35 <- rows 0..3 (pos).
__device__ __forceinline__ void pack_weights(
    const float* __restrict__ W0g, const float* __restrict__ W1g,
    const float* __restrict__ W2g, unsigned short* __restrict__ wp, int t)
{
    for (int idx = t; idx < W0SZ; idx += 256) {
        int col = idx / W0P, k = idx - col * W0P;
        float w = (k < 32) ? W0g[(k + 4) * D1 + col]
                           : ((k < 36) ? W0g[(k - 32) * D1 + col] : 0.0f);
        wp[idx] = f2bf(w);
    }
    for (int idx = t; idx < W1SZ; idx += 256) {
        int col = idx / W1P, k = idx - col * W1P;
        wp[W0SZ + idx] = f2bf((k < D2) ? W1g[k * D1 + col] : 0.0f);
    }
    for (int idx = t; idx < W2SZ; idx += 256) {
        int col = idx / W1P, k = idx - col * W1P;
        wp[W0SZ + W1SZ + idx] = f2bf((k < D2) ? W2g[k * OUTD + col] : 0.0f);
    }
}

// Fast stage: coalesced int4 copy of the pre-packed weight block + biases.
__device__ __forceinline__ void stage_packed(
    unsigned short* Wall, float* bs, const unsigned short* __restrict__ wpack,
    const float* __restrict__ b0g, const float* __restrict__ b1g,
    const float* __restrict__ b2g, int t)
{
    for (int idx = t; idx < WPACK / 8; idx += NT)
        ((int4*)Wall)[idx] = ((const int4*)wpack)[idx];
    for (int idx = t; idx < 192; idx += NT)
        bs[idx] = (idx < 80) ? b0g[idx] : (idx < 160 ? b1g[idx - 80] : b2g[idx - 160]);
}

// Per-wave 16-row chunk MLP (R12-verified structure — best known).
// L1 B-operands arrive IN REGISTERS; H1/H2 relayout via wave-private LDS rows
// (no barriers; same-wave DS ordering). Out = 32 floats at Trow[0..64) bf16
// region. Pad [80..96) pre-zeroed once per wave. cb loops unroll-1 ON
// PURPOSE — every widened-live-set attempt spilled to scratch under the reg
// cap (full unroll R2/R3, VGPR w2f R6/R7, unroll-2 R9, frag rotation R14).
// Spill tripwire: FETCH/WRITE counters.
__device__ __forceinline__ void mlp_chunk(
    int4 featsi, int4 posfi, unsigned short* Trow,
    const unsigned short* W0h, const unsigned short* W1h,
    const unsigned short* W2h, const float* bs, int lm, int quad)
{
    bf16x8 b1f0 = *(bf16x8*)&featsi;
    bf16x8 b1f1 = *(bf16x8*)&posfi;
    // ---- L1: K=64 (feats+pos+pad) -> 80, gelu ----
#pragma unroll 1
    for (int cb = 0; cb < 5; ++cb) {
        f4 acc = *(const f4*)&bs[cb * 16 + quad * 4];
        bf16x8 a0 = *(const bf16x8*)&W0h[(cb * 16 + lm) * W0P + quad * 8];
        bf16x8 a1 = *(const bf16x8*)&W0h[(cb * 16 + lm) * W0P + 32 + quad * 8];
        acc = __builtin_amdgcn_mfma_f32_16x16x32_bf16(a0, b1f0, acc, 0, 0, 0);
        acc = __builtin_amdgcn_mfma_f32_16x16x32_bf16(a1, b1f1, acc, 0, 0, 0);
        *(int2*)&Trow[cb * 16 + quad * 4] =
            make_int2(pk2(gelu_f(acc.x), gelu_f(acc.y)),
                      pk2(gelu_f(acc.z), gelu_f(acc.w)));
    }
    // ---- L2: 80(pad 96) -> 80, gelu ----
    bf16x8 b2f[3];
    b2f[0] = *(const bf16x8*)&Trow[quad * 8];
    b2f[1] = *(const bf16x8*)&Trow[32 + quad * 8];
    b2f[2] = *(const bf16x8*)&Trow[64 + quad * 8];
#pragma unroll 1
    for (int cb = 0; cb < 5; ++cb) {
        f4 acc = *(const f4*)&bs[80 + cb * 16 + quad * 4];
        const unsigned short* wh = &W1h[(cb * 16 + lm) * W1P + quad * 8];
        bf16x8 h0 = *(const bf16x8*)&wh[0];
        bf16x8 h1 = *(const bf16x8*)&wh[32];
        bf16x8 h2 = *(const bf16x8*)&wh[64];
        acc = __builtin_amdgcn_mfma_f32_16x16x32_bf16(h0, b2f[0], acc, 0, 0, 0);
        acc = __builtin_amdgcn_mfma_f32_16x16x32_bf16(h1, b2f[1], acc, 0, 0, 0);
        acc = __builtin_amdgcn_mfma_f32_16x16x32_bf16(h2, b2f[2], acc, 0, 0, 0);
        *(int2*)&Trow[cb * 16 + quad * 4] =
            make_int2(pk2(gelu_f(acc.x), gelu_f(acc.y)),
                      pk2(gelu_f(acc.z), gelu_f(acc.w)));
    }
    // ---- L3: 80(pad 96) -> 32, fp32 out at Trow floats [0..32) ----
    bf16x8 b3f[3];
    b3f[0] = *(const bf16x8*)&Trow[quad * 8];
    b3f[1] = *(const bf16x8*)&Trow[32 + quad * 8];
    b3f[2] = *(const bf16x8*)&Trow[64 + quad * 8];
    float* po = (float*)Trow;
#pragma unroll 1
    for (int cb = 0; cb < 2; ++cb) {
        f4 acc = *(const f4*)&bs[160 + cb * 16 + quad * 4];
        const unsigned short* wh = &W2h[(cb * 16 + lm) * W1P + quad * 8];
        bf16x8 h0 = *(const bf16x8*)&wh[0];
        bf16x8 h1 = *(const bf16x8*)&wh[32];
        bf16x8 h2 = *(const bf16x8*)&wh[64];
        acc = __builtin_amdgcn_mfma_f32_16x16x32_bf16(h0, b3f[0], acc, 0, 0, 0);
        acc = __builtin_amdgcn_mfma_f32_16x16x32_bf16(h1, b3f[1], acc, 0, 0, 0);
        acc = __builtin_amdgcn_mfma_f32_16x16x32_bf16(h2, b3f[2], acc, 0, 0, 0);
        *(f4*)&po[cb * 16 + quad * 4] = acc;
    }
}

// ---- merged projection + scan + weight-pack ----
// blocks 0..767 proj; 768 scan; 769 pack it0 weights; 770 pack it1 weights.
__global__ __launch_bounds__(256) void proj_scan_kernel(
    const float* __restrict__ inp, const float* __restrict__ grid_in,
    const float* __restrict__ W0, const float* __restrict__ b0,
    const float* __restrict__ W1, const float* __restrict__ b1,
    unsigned short* __restrict__ f0b,
    const int* __restrict__ counts, int* __restrict__ offsets,
    const float* __restrict__ i0W0, const float* __restrict__ i0W1,
    const float* __restrict__ i0W2, unsigned short* __restrict__ wpack0,
    const float* __restrict__ i1W0, const float* __restrict__ i1W1,
    const float* __restrict__ i1W2, unsigned short* __restrict__ wpack1)
{
    const int t = threadIdx.x;
    if (blockIdx.x == 769) { pack_weights(i0W0, i0W1, i0W2, wpack0, t); return; }
    if (blockIdx.x == 770) { pack_weights(i1W0, i1W1, i1W2, wpack1, t); return; }
    if (blockIdx.x == 768) {
        __shared__ int ws2[4], wx2[4];
        const int lane = t & 63, wave = t >> 6;
        int4 a[8];
#pragma unroll
        for (int i = 0; i < 8; ++i) a[i] = ((const int4*)counts)[t * 8 + i];
        int s = 0;
#pragma unroll
        for (int i = 0; i < 8; ++i) s += a[i].x + a[i].y + a[i].z + a[i].w;
        int x = s;
#pragma unroll
        for (int d = 1; d < 64; d <<= 1) {
            int y = __shfl_up(x, d);
            if (lane >= d) x += y;
        }
        if (lane == 63) ws2[wave] = x;
        __syncthreads();
        if (t == 0) {
            wx2[0] = 0;
            wx2[1] = ws2[0];
            wx2[2] = ws2[0] + ws2[1];
            wx2[3] = ws2[0] + ws2[1] + ws2[2];
        }
        __syncthreads();
        int base = wx2[wave] + (x - s);
#pragma unroll
        for (int i = 0; i < 8; ++i) {
            int4 c = a[i];
            int4 o;
            o.x = base; base += c.x;
            o.y = base; base += c.y;
            o.z = base; base += c.z;
            o.w = base; base += c.w;
            ((int4*)offsets)[t * 8 + i] = o;
        }
        return;
    }
    __shared__ float W0s[8 * 64];
    __shared__ float W1s[64 * OUTD];
    __shared__ float xs[32 * 8];
    __shared__ float H[32 * 64];
    const int r0 = blockIdx.x * 32;
    for (int idx = t; idx < 512; idx += 256) W0s[idx] = W0[idx];
    for (int idx = t; idx < 64 * OUTD; idx += 256) W1s[idx] = W1[idx];
    xs[t] = inp[r0 * 8 + t];
    if (t < 32) {
        int row = r0 + t, n = row / 3, v = row - n * 3;
        *(int*)(f0b + ((size_t)(v << 13) + n) * RP + 32) =
            pk2(grid_in[2 * n], grid_in[2 * n + 1]);
    }
    __syncthreads();
#pragma unroll 1
    for (int p = 0; p < 8; ++p) {
        int o = t + 256 * p, r = o >> 6, col = o & 63;
        float s = b0[col];
#pragma unroll
        for (int k = 0; k < 8; ++k) s += xs[r * 8 + k] * W0s[k * 64 + col];
        H[o] = gelu_f(s);
    }
    __syncthreads();
#pragma unroll 1
    for (int p = 0; p < 4; ++p) {
        int o = t + 256 * p, r = o >> 5, c = o & 31;
        float s = b1[c];
#pragma unroll 8
        for (int k = 0; k < 64; ++k) s += H[r * 64 + k] * W1s[k * OUTD + c];
        int row = r0 + r;
        int n = row / 3, v = row - n * 3;
        f0b[((size_t)(v << 13) + n) * RP + c] = f2bf(s);
    }
}

// ---- edge MLP + owner-computes segment mean (R12 structure) ----
// 12 waves x 768 thr; LDS ~81.9 KB -> 2 blocks/CU (24 waves/CU).
__global__ __launch_bounds__(768, 6) void agg_kernel(
    const float* __restrict__ grid_in, const unsigned short* __restrict__ f0b,
    const int* __restrict__ nbr_index, const int* __restrict__ offsets,
    const int* __restrict__ counts,
    const unsigned short* __restrict__ wpack,
    const float* __restrict__ b0g, const float* __restrict__ b1g,
    const float* __restrict__ b2g,
    unsigned short* __restrict__ f1b)
{
    __shared__ __attribute__((aligned(16))) unsigned short Tb[NWAVES * 16 * TPCH];
    __shared__ __attribute__((aligned(16))) unsigned short Wall[WPACK];
    __shared__ __attribute__((aligned(16))) float bs[192];
    __shared__ __attribute__((aligned(16))) float accH[VARS * PB * 32];
    __shared__ int offs[PB + 1];
    __shared__ int px2b[PB];
    __shared__ float invb[PB];

    const unsigned short* W0h = Wall;
    const unsigned short* W1h = Wall + W0SZ;
    const unsigned short* W2h = Wall + W0SZ + W1SZ;

    const int t = threadIdx.x;
    const int lane = t & 63, wave = t >> 6;
    const int lm = lane & 15, quad = lane >> 4;
    const int p0 = blockIdx.x * PB;

    stage_packed(Wall, bs, wpack, b0g, b1g, b2g, t);
    if (t < PB) {
        offs[t] = offsets[p0 + t];
        int c = counts[p0 + t];
        invb[t] = 1.0f / (float)(c > 1 ? c : 1);
        px2b[t] = pk2(grid_in[2 * (p0 + t)], grid_in[2 * (p0 + t) + 1]);
    }
    if (t == PB) offs[PB] = offsets[p0 + PB - 1] + counts[p0 + PB - 1];
    for (int idx = t; idx < VARS * PB * 32; idx += NT) accH[idx] = 0.0f;
    __syncthreads();

    // zero persistent pad [80..96) of this wave's 16 rows (never rewritten)
    unsigned short* TbW = Tb + (wave * 16) * TPCH;
    if (lane < 32)
        *(int4*)(TbW + (lane >> 1) * TPCH + 80 + (lane & 1) * 8) = make_int4(0, 0, 0, 0);

    const int e0 = offs[0];
    const int cntT = offs[PB] - e0;
    const int Rb = VARS * cntT;
    const int nch = (Rb + 15) >> 4;

    unsigned short* Trow = TbW + lm * TPCH;

    // prefetch state for chunk ch
    int pkey; int4 pfeats, pposf;
    {
        int myrow = (wave << 4) + lm;
        pkey = -1; pfeats = make_int4(0,0,0,0); pposf = make_int4(0,0,0,0);
        if (myrow < Rb) {
            int myv = (myrow >= 2 * cntT) ? 2 : ((myrow >= cntT) ? 1 : 0);
            int e = e0 + myrow - myv * cntT;
            int myj = nbr_index[e];
            int lp = 0;
#pragma unroll
            for (int l = 1; l < PB; ++l) lp += (e >= offs[l]);
            pkey = myv * PB + lp;
            const unsigned short* rec = f0b + ((size_t)(myv << 13) + myj) * RP;
            pfeats = ((const int4*)rec)[quad];
            if (quad == 0) pposf = make_int4(*(const int*)(rec + 32), px2b[lp], 0, 0);
        }
    }

    for (int ch = wave; ch < nch; ch += NWAVES) {
        int ckey = pkey; int4 cfeats = pfeats, cposf = pposf;
        // issue next chunk's gather before the MLP (latency hides behind MFMA)
        int nc = ch + NWAVES;
        pkey = -1; pfeats = make_int4(0,0,0,0); pposf = make_int4(0,0,0,0);
        if (nc < nch) {
            int myrow = (nc << 4) + lm;
            if (myrow < Rb) {
                int myv = (myrow >= 2 * cntT) ? 2 : ((myrow >= cntT) ? 1 : 0);
                int e = e0 + myrow - myv * cntT;
                int myj = nbr_index[e];
                int lp = 0;
#pragma unroll
                for (int l = 1; l < PB; ++l) lp += (e >= offs[l]);
                pkey = myv * PB + lp;
                const unsigned short* rec = f0b + ((size_t)(myv << 13) + myj) * RP;
                pfeats = ((const int4*)rec)[quad];
                if (quad == 0) pposf = make_int4(*(const int*)(rec + 32), px2b[lp], 0, 0);
            }
        }
        if (ckey < 0) { cfeats = make_int4(0,0,0,0); cposf = make_int4(0,0,0,0); }
        mlp_chunk(cfeats, cposf, Trow, W0h, W1h, W2h, bs, lm, quad);
        // keyed reduction of this wave's 16 rows into block accumulator
        int col = lane & 31, eo = lane >> 5;
#pragma unroll 1
        for (int e2 = eo; e2 < 16; e2 += 2) {
            int k = __shfl(ckey, e2);
            if (k >= 0)
                atomicAdd(&accH[k * 32 + col], ((const float*)(TbW + e2 * TPCH))[col]);
        }
    }
    __syncthreads();
    for (int idx = t; idx < VARS * PB * OUTD; idx += NT) {
        int key = idx >> 5, c = idx & 31;
        int v = key >> 4, lp = key & 15;
        size_t rec = ((size_t)(v << 13) + p0 + lp) * RP;
        float val = accH[key * 32 + c] * invb[lp] + bf2f(f0b[rec + c]);
        f1b[rec + c] = f2bf(val);
    }
    if (t < VARS * PB) {
        int v = t >> 4, lp = t & 15;
        *(int*)(f1b + ((size_t)(v << 13) + p0 + lp) * RP + 32) = px2b[lp];
    }
}

// ---- kNN MLP + mean over K ----
__global__ __launch_bounds__(768, 6) void last_kernel(
    const unsigned short* __restrict__ f1b, const float* __restrict__ grid_out,
    const int* __restrict__ nbr_last,
    const unsigned short* __restrict__ wpack,
    const float* __restrict__ b0g, const float* __restrict__ b1g,
    const float* __restrict__ b2g,
    float* __restrict__ out)
{
    __shared__ __attribute__((aligned(16))) unsigned short Tb[NWAVES * 16 * TPCH];
    __shared__ __attribute__((aligned(16))) unsigned short Wall[WPACK];
    __shared__ __attribute__((aligned(16))) float bs[192];
    __shared__ __attribute__((aligned(16))) float accH[LPTS * VARS * 32];
    __shared__ int pxo2b[LPTS];

    const unsigned short* W0h = Wall;
    const unsigned short* W1h = Wall + W0SZ;
    const unsigned short* W2h = Wall + W0SZ + W1SZ;

    const int t = threadIdx.x;
    const int lane = t & 63, wave = t >> 6;
    const int lm = lane & 15, quad = lane >> 4;
    const int m0 = blockIdx.x * LPTS;

    stage_packed(Wall, bs, wpack, b0g, b1g, b2g, t);
    if (t < LPTS)
        pxo2b[t] = pk2(grid_out[2 * (m0 + t)], grid_out[2 * (m0 + t) + 1]);
    for (int idx = t; idx < LPTS * VARS * 32; idx += NT) accH[idx] = 0.0f;
    __syncthreads();
    unsigned short* TbW = Tb + (wave * 16) * TPCH;
    if (lane < 32)
        *(int4*)(TbW + (lane >> 1) * TPCH + 80 + (lane & 1) * 8) = make_int4(0, 0, 0, 0);

    const int Rb = LPTS * VARS * KLAST;   // 240
    const int nch = (Rb + 15) >> 4;       // 15
    unsigned short* Trow = TbW + lm * TPCH;

    for (int ch = wave; ch < nch; ch += NWAVES) {
        int myrow = (ch << 4) + lm;
        int ckey = -1; int4 cfeats = make_int4(0,0,0,0), cposf = make_int4(0,0,0,0);
        if (myrow < Rb) {
            int lp = myrow / 30, rr = myrow - lp * 30;
            int v = rr / KLAST, kk = rr - v * KLAST;
            int myj = nbr_last[(m0 + lp) * KLAST + kk];
            ckey = lp * VARS + v;
            const unsigned short* rec = f1b + ((size_t)(v << 13) + myj) * RP;
            cfeats = ((const int4*)rec)[quad];
            if (quad == 0) cposf = make_int4(*(const int*)(rec + 32), pxo2b[lp], 0, 0);
        }
        mlp_chunk(cfeats, cposf, Trow, W0h, W1h, W2h, bs, lm, quad);
        int col = lane & 31, eo = lane >> 5;
#pragma unroll 1
        for (int e2 = eo; e2 < 16; e2 += 2) {
            int k = __shfl(ckey, e2);
            if (k >= 0)
                atomicAdd(&accH[k * 32 + col], ((const float*)(TbW + e2 * TPCH))[col]);
        }
    }
    __syncthreads();
    if (t < LPTS * VARS * OUTD) {
        int key = t >> 5, c = t & 31;
        int lp = key / VARS, v = key - lp * VARS;
        out[((size_t)(m0 + lp) * VARS + v) * OUTD + c] = accH[key * 32 + c] * (1.0f / KLAST);
    }
}

extern "C" void kernel_launch(void* const* d_in, const int* in_sizes, int n_in,
                              void* d_out, int out_size, void* d_ws, size_t ws_size,
                              hipStream_t stream) {
    const float* inp      = (const float*)d_in[0];
    const float* grid_in  = (const float*)d_in[1];
    const float* grid_out = (const float*)d_in[2];
    const float* pW0 = (const float*)d_in[3];
    const float* pb0 = (const float*)d_in[4];
    const float* pW1 = (const float*)d_in[5];
    const float* pb1 = (const float*)d_in[6];
    const float* i0W0 = (const float*)d_in[7];
    const float* i0b0 = (const float*)d_in[8];
    const float* i0W1 = (const float*)d_in[9];
    const float* i0b1 = (const float*)d_in[10];
    const float* i0W2 = (const float*)d_in[11];
    const float* i0b2 = (const float*)d_in[12];
    const float* i1W0 = (const float*)d_in[13];
    const float* i1b0 = (const float*)d_in[14];
    const float* i1W1 = (const float*)d_in[15];
    const float* i1b1 = (const float*)d_in[16];
    const float* i1W2 = (const float*)d_in[17];
    const float* i1b2 = (const float*)d_in[18];
    const int* nbr_index  = (const int*)d_in[19];
    const int* nbr_counts = (const int*)d_in[21];
    const int* nbr_last   = (const int*)d_in[22];

    unsigned short* f0b = (unsigned short*)d_ws;                      // 3*8192*40 bf16
    unsigned short* f1b = f0b + (size_t)VARS * N_PTS * RP;            // 3*8192*40 bf16
    int* offsets = (int*)(f1b + (size_t)VARS * N_PTS * RP);           // N ints
    unsigned short* wpack0 = (unsigned short*)(offsets + N_PTS);      // 17408 bf16
    unsigned short* wpack1 = wpack0 + WPACK;                          // 17408 bf16

    proj_scan_kernel<<<771, 256, 0, stream>>>(inp, grid_in, pW0, pb0, pW1, pb1,
                                              f0b, nbr_counts, offsets,
                                              i0W0, i0W1, i0W2, wpack0,
                                              i1W0, i1W1, i1W2, wpack1);
    agg_kernel<<<N_PTS / PB, NT, 0, stream>>>(grid_in, f0b, nbr_index, offsets,
                                              nbr_counts, wpack0,
                                              i0b0, i0b1, i0b2, f1b);
    last_kernel<<<M_PTS / LPTS, NT, 0, stream>>>(f1b, grid_out, nbr_last, wpack1,
                                                 i1b0, i1b1, i1b2,
                                                 (float*)d_out);
}

// Round 16
// 307.617 us; speedup vs baseline: 1.1128x; 1.0423x over previous
//
#include <hip/hip_runtime.h>
#include <hip/hip_bf16.h>
#include <math.h>

#define N_PTS 8192
#define M_PTS 2048
#define KLAST 10
#define VARS 3
#define OUTD 32
#define D1 80
#define D2 80
#define PB 8          // points per agg block -> 1024 blocks, 4 blocks/CU
#define LPTS 4        // output points per last block -> 512 blocks
#define NT 512        // 8 waves per block
#define NWAVES 8
#define TPCH 104      // Tb row pitch in bf16 (208 B; stride-52 dwords -> 2-way banks)
#define W0P 72        // W0 K-pitch (K=64 used: feats 0..32, pos 32..36, pad ..64)
#define W1P 104       // W1/W2 K-pitch (K=80 padded to 96)
#define RP 40         // f0b/f1b record pitch in bf16 (80 B: [32 feats | ypos | pad])
#define W0SZ (D1 * W0P)              // 5760
#define W1SZ (D1 * W1P)              // 8320
#define W2SZ (OUTD * W1P)            // 3328
#define WPACK (W0SZ + W1SZ + W2SZ)   // 17408 bf16 elems per weight set

typedef float f4 __attribute__((ext_vector_type(4)));
typedef short bf16x8 __attribute__((ext_vector_type(8)));

// lean inf-safe tanh-gelu: gelu = x - x*rcp(exp2(x*(A+B*x^2))+1); err ~3e-4.
__device__ __forceinline__ float gelu_f(float x) {
    float x2 = x * x;
    float s = x * __builtin_fmaf(0.1029418f, x2, 2.3022083f);
    float u = __builtin_amdgcn_exp2f(s);
    float r = __builtin_amdgcn_rcpf(u + 1.0f);
    return __builtin_fmaf(-x, r, x);
}
__device__ __forceinline__ unsigned short f2bf(float x) {
    unsigned int u = __float_as_uint(x);
    u += 0x7FFF + ((u >> 16) & 1);
    return (unsigned short)(u >> 16);
}
__device__ __forceinline__ float bf2f(unsigned short h) {
    return __uint_as_float(((unsigned int)h) << 16);
}
// packed RNE f32x2 -> bf16x2 (v_cvt_pk_bf16_f32 on gfx950)
__device__ __forceinline__ int pk2(float a, float b) {
    __hip_bfloat162 h = __float22bfloat162_rn(float2{a, b});
    int r; __builtin_memcpy(&r, &h, 4); return r;
}

// One-time pack: single-bf16 weights transposed [col][k], K zero-padded, in
// the exact per-lane MFMA fragment layout. Consumers read fragments STRAIGHT
// FROM GLOBAL (coalesced 16B/lane, L1/L2-resident 35 KB set shared by all
// blocks on a CU) — this frees 34.8 KB of LDS per block, enabling 4 blocks
// of 8 waves per CU = 32 waves/CU (HW max; was 24). W0 k-order REORDERED to
// record layout: k 0..31 <- W0g rows 4..35 (features), k 32..35 <- rows 0..3.
__device__ __forceinline__ void pack_weights(
    const float* __restrict__ W0g, const float* __restrict__ W1g,
    const float* __restrict__ W2g, unsigned short* __restrict__ wp, int t)
{
    for (int idx = t; idx < W0SZ; idx += 256) {
        int col = idx / W0P, k = idx - col * W0P;
        float w = (k < 32) ? W0g[(k + 4) * D1 + col]
                           : ((k < 36) ? W0g[(k - 32) * D1 + col] : 0.0f);
        wp[idx] = f2bf(w);
    }
    for (int idx = t; idx < W1SZ; idx += 256) {
        int col = idx / W1P, k = idx - col * W1P;
        wp[W0SZ + idx] = f2bf((k < D2) ? W1g[k * D1 + col] : 0.0f);
    }
    for (int idx = t; idx < W2SZ; idx += 256) {
        int col = idx / W1P, k = idx - col * W1P;
        wp[W0SZ + W1SZ + idx] = f2bf((k < D2) ? W2g[k * OUTD + col] : 0.0f);
    }
}

// Per-wave 16-row chunk MLP (R12-verified structure; weights read from
// GLOBAL wpack). L1 B-operands arrive IN REGISTERS; H1/H2 relayout via
// wave-private LDS rows (no barriers; same-wave DS ordering). Out = 32
// floats at Trow[0..64) bf16 region. Pad [80..96) pre-zeroed once per wave.
// cb loops unroll-1 ON PURPOSE — every widened-live-set attempt spilled to
// scratch under the reg cap (full unroll R2/R3, VGPR w2f R6/R7, unroll-2 R9,
// frag rotation R14). Spill tripwire: FETCH/WRITE counters.
__device__ __forceinline__ void mlp_chunk(
    int4 featsi, int4 posfi, unsigned short* Trow,
    const unsigned short* __restrict__ W0h,
    const unsigned short* __restrict__ W1h,
    const unsigned short* __restrict__ W2h,
    const float* bs, int lm, int quad)
{
    bf16x8 b1f0 = *(bf16x8*)&featsi;
    bf16x8 b1f1 = *(bf16x8*)&posfi;
    // ---- L1: K=64 (feats+pos+pad) -> 80, gelu ----
#pragma unroll 1
    for (int cb = 0; cb < 5; ++cb) {
        f4 acc = *(const f4*)&bs[cb * 16 + quad * 4];
        bf16x8 a0 = *(const bf16x8*)&W0h[(cb * 16 + lm) * W0P + quad * 8];
        bf16x8 a1 = *(const bf16x8*)&W0h[(cb * 16 + lm) * W0P + 32 + quad * 8];
        acc = __builtin_amdgcn_mfma_f32_16x16x32_bf16(a0, b1f0, acc, 0, 0, 0);
        acc = __builtin_amdgcn_mfma_f32_16x16x32_bf16(a1, b1f1, acc, 0, 0, 0);
        *(int2*)&Trow[cb * 16 + quad * 4] =
            make_int2(pk2(gelu_f(acc.x), gelu_f(acc.y)),
                      pk2(gelu_f(acc.z), gelu_f(acc.w)));
    }
    // ---- L2: 80(pad 96) -> 80, gelu ----
    bf16x8 b2f[3];
    b2f[0] = *(const bf16x8*)&Trow[quad * 8];
    b2f[1] = *(const bf16x8*)&Trow[32 + quad * 8];
    b2f[2] = *(const bf16x8*)&Trow[64 + quad * 8];
#pragma unroll 1
    for (int cb = 0; cb < 5; ++cb) {
        f4 acc = *(const f4*)&bs[80 + cb * 16 + quad * 4];
        const unsigned short* wh = &W1h[(cb * 16 + lm) * W1P + quad * 8];
        bf16x8 h0 = *(const bf16x8*)&wh[0];
        bf16x8 h1 = *(const bf16x8*)&wh[32];
        bf16x8 h2 = *(const bf16x8*)&wh[64];
        acc = __builtin_amdgcn_mfma_f32_16x16x32_bf16(h0, b2f[0], acc, 0, 0, 0);
        acc = __builtin_amdgcn_mfma_f32_16x16x32_bf16(h1, b2f[1], acc, 0, 0, 0);
        acc = __builtin_amdgcn_mfma_f32_16x16x32_bf16(h2, b2f[2], acc, 0, 0, 0);
        *(int2*)&Trow[cb * 16 + quad * 4] =
            make_int2(pk2(gelu_f(acc.x), gelu_f(acc.y)),
                      pk2(gelu_f(acc.z), gelu_f(acc.w)));
    }
    // ---- L3: 80(pad 96) -> 32, fp32 out at Trow floats [0..32) ----
    bf16x8 b3f[3];
    b3f[0] = *(const bf16x8*)&Trow[quad * 8];
    b3f[1] = *(const bf16x8*)&Trow[32 + quad * 8];
    b3f[2] = *(const bf16x8*)&Trow[64 + quad * 8];
    float* po = (float*)Trow;
#pragma unroll 1
    for (int cb = 0; cb < 2; ++cb) {
        f4 acc = *(const f4*)&bs[160 + cb * 16 + quad * 4];
        const unsigned short* wh = &W2h[(cb * 16 + lm) * W1P + quad * 8];
        bf16x8 h0 = *(const bf16x8*)&wh[0];
        bf16x8 h1 = *(const bf16x8*)&wh[32];
        bf16x8 h2 = *(const bf16x8*)&wh[64];
        acc = __builtin_amdgcn_mfma_f32_16x16x32_bf16(h0, b3f[0], acc, 0, 0, 0);
        acc = __builtin_amdgcn_mfma_f32_16x16x32_bf16(h1, b3f[1], acc, 0, 0, 0);
        acc = __builtin_amdgcn_mfma_f32_16x16x32_bf16(h2, b3f[2], acc, 0, 0, 0);
        *(f4*)&po[cb * 16 + quad * 4] = acc;
    }
}

// ---- merged projection + scan + weight-pack ----
// blocks 0..767 proj; 768 scan; 769 pack it0 weights; 770 pack it1 weights.
__global__ __launch_bounds__(256) void proj_scan_kernel(
    const float* __restrict__ inp, const float* __restrict__ grid_in,
    const float* __restrict__ W0, const float* __restrict__ b0,
    const float* __restrict__ W1, const float* __restrict__ b1,
    unsigned short* __restrict__ f0b,
    const int* __restrict__ counts, int* __restrict__ offsets,
    const float* __restrict__ i0W0, const float* __restrict__ i0W1,
    const float* __restrict__ i0W2, unsigned short* __restrict__ wpack0,
    const float* __restrict__ i1W0, const float* __restrict__ i1W1,
    const float* __restrict__ i1W2, unsigned short* __restrict__ wpack1)
{
    const int t = threadIdx.x;
    if (blockIdx.x == 769) { pack_weights(i0W0, i0W1, i0W2, wpack0, t); return; }
    if (blockIdx.x == 770) { pack_weights(i1W0, i1W1, i1W2, wpack1, t); return; }
    if (blockIdx.x == 768) {
        __shared__ int ws2[4], wx2[4];
        const int lane = t & 63, wave = t >> 6;
        int4 a[8];
#pragma unroll
        for (int i = 0; i < 8; ++i) a[i] = ((const int4*)counts)[t * 8 + i];
        int s = 0;
#pragma unroll
        for (int i = 0; i < 8; ++i) s += a[i].x + a[i].y + a[i].z + a[i].w;
        int x = s;
#pragma unroll
        for (int d = 1; d < 64; d <<= 1) {
            int y = __shfl_up(x, d);
            if (lane >= d) x += y;
        }
        if (lane == 63) ws2[wave] = x;
        __syncthreads();
        if (t == 0) {
            wx2[0] = 0;
            wx2[1] = ws2[0];
            wx2[2] = ws2[0] + ws2[1];
            wx2[3] = ws2[0] + ws2[1] + ws2[2];
        }
        __syncthreads();
        int base = wx2[wave] + (x - s);
#pragma unroll
        for (int i = 0; i < 8; ++i) {
            int4 c = a[i];
            int4 o;
            o.x = base; base += c.x;
            o.y = base; base += c.y;
            o.z = base; base += c.z;
            o.w = base; base += c.w;
            ((int4*)offsets)[t * 8 + i] = o;
        }
        return;
    }
    __shared__ float W0s[8 * 64];
    __shared__ float W1s[64 * OUTD];
    __shared__ float xs[32 * 8];
    __shared__ float H[32 * 64];
    const int r0 = blockIdx.x * 32;
    for (int idx = t; idx < 512; idx += 256) W0s[idx] = W0[idx];
    for (int idx = t; idx < 64 * OUTD; idx += 256) W1s[idx] = W1[idx];
    xs[t] = inp[r0 * 8 + t];
    if (t < 32) {
        int row = r0 + t, n = row / 3, v = row - n * 3;
        *(int*)(f0b + ((size_t)(v << 13) + n) * RP + 32) =
            pk2(grid_in[2 * n], grid_in[2 * n + 1]);
    }
    __syncthreads();
#pragma unroll 1
    for (int p = 0; p < 8; ++p) {
        int o = t + 256 * p, r = o >> 6, col = o & 63;
        float s = b0[col];
#pragma unroll
        for (int k = 0; k < 8; ++k) s += xs[r * 8 + k] * W0s[k * 64 + col];
        H[o] = gelu_f(s);
    }
    __syncthreads();
#pragma unroll 1
    for (int p = 0; p < 4; ++p) {
        int o = t + 256 * p, r = o >> 5, c = o & 31;
        float s = b1[c];
#pragma unroll 8
        for (int k = 0; k < 64; ++k) s += H[r * 64 + k] * W1s[k * OUTD + c];
        int row = r0 + r;
        int n = row / 3, v = row - n * 3;
        f0b[((size_t)(v << 13) + n) * RP + c] = f2bf(s);
    }
}

// ---- edge MLP + owner-computes segment mean ----
// 8 waves x 512 thr, PB=8 -> 1024 blocks; LDS ~33.6 KB -> 4 blocks/CU =
// 32 waves/CU (HW max). Weights from global wpack via L1/L2.
__global__ __launch_bounds__(512, 8) void agg_kernel(
    const float* __restrict__ grid_in, const unsigned short* __restrict__ f0b,
    const int* __restrict__ nbr_index, const int* __restrict__ offsets,
    const int* __restrict__ counts,
    const unsigned short* __restrict__ wpack,
    const float* __restrict__ b0g, const float* __restrict__ b1g,
    const float* __restrict__ b2g,
    unsigned short* __restrict__ f1b)
{
    __shared__ __attribute__((aligned(16))) unsigned short Tb[NWAVES * 16 * TPCH];
    __shared__ __attribute__((aligned(16))) float bs[192];
    __shared__ __attribute__((aligned(16))) float accH[VARS * PB * 32];
    __shared__ int offs[PB + 1];
    __shared__ int px2b[PB];
    __shared__ float invb[PB];

    const unsigned short* W0h = wpack;
    const unsigned short* W1h = wpack + W0SZ;
    const unsigned short* W2h = wpack + W0SZ + W1SZ;

    const int t = threadIdx.x;
    const int lane = t & 63, wave = t >> 6;
    const int lm = lane & 15, quad = lane >> 4;
    const int p0 = blockIdx.x * PB;

    for (int idx = t; idx < 192; idx += NT)
        bs[idx] = (idx < 80) ? b0g[idx] : (idx < 160 ? b1g[idx - 80] : b2g[idx - 160]);
    if (t < PB) {
        offs[t] = offsets[p0 + t];
        int c = counts[p0 + t];
        invb[t] = 1.0f / (float)(c > 1 ? c : 1);
        px2b[t] = pk2(grid_in[2 * (p0 + t)], grid_in[2 * (p0 + t) + 1]);
    }
    if (t == PB) offs[PB] = offsets[p0 + PB - 1] + counts[p0 + PB - 1];
    for (int idx = t; idx < VARS * PB * 32; idx += NT) accH[idx] = 0.0f;
    __syncthreads();

    // zero persistent pad [80..96) of this wave's 16 rows (never rewritten)
    unsigned short* TbW = Tb + (wave * 16) * TPCH;
    if (lane < 32)
        *(int4*)(TbW + (lane >> 1) * TPCH + 80 + (lane & 1) * 8) = make_int4(0, 0, 0, 0);

    const int e0 = offs[0];
    const int cntT = offs[PB] - e0;
    const int Rb = VARS * cntT;
    const int nch = (Rb + 15) >> 4;

    unsigned short* Trow = TbW + lm * TPCH;

    // prefetch state for chunk ch
    int pkey; int4 pfeats, pposf;
    {
        int myrow = (wave << 4) + lm;
        pkey = -1; pfeats = make_int4(0,0,0,0); pposf = make_int4(0,0,0,0);
        if (myrow < Rb) {
            int myv = (myrow >= 2 * cntT) ? 2 : ((myrow >= cntT) ? 1 : 0);
            int e = e0 + myrow - myv * cntT;
            int myj = nbr_index[e];
            int lp = 0;
#pragma unroll
            for (int l = 1; l < PB; ++l) lp += (e >= offs[l]);
            pkey = myv * PB + lp;
            const unsigned short* rec = f0b + ((size_t)(myv << 13) + myj) * RP;
            pfeats = ((const int4*)rec)[quad];
            if (quad == 0) pposf = make_int4(*(const int*)(rec + 32), px2b[lp], 0, 0);
        }
    }

    for (int ch = wave; ch < nch; ch += NWAVES) {
        int ckey = pkey; int4 cfeats = pfeats, cposf = pposf;
        // issue next chunk's gather before the MLP (latency hides behind MFMA)
        int nc = ch + NWAVES;
        pkey = -1; pfeats = make_int4(0,0,0,0); pposf = make_int4(0,0,0,0);
        if (nc < nch) {
            int myrow = (nc << 4) + lm;
            if (myrow < Rb) {
                int myv = (myrow >= 2 * cntT) ? 2 : ((myrow >= cntT) ? 1 : 0);
                int e = e0 + myrow - myv * cntT;
                int myj = nbr_index[e];
                int lp = 0;
#pragma unroll
                for (int l = 1; l < PB; ++l) lp += (e >= offs[l]);
                pkey = myv * PB + lp;
                const unsigned short* rec = f0b + ((size_t)(myv << 13) + myj) * RP;
                pfeats = ((const int4*)rec)[quad];
                if (quad == 0) pposf = make_int4(*(const int*)(rec + 32), px2b[lp], 0, 0);
            }
        }
        if (ckey < 0) { cfeats = make_int4(0,0,0,0); cposf = make_int4(0,0,0,0); }
        mlp_chunk(cfeats, cposf, Trow, W0h, W1h, W2h, bs, lm, quad);
        // keyed reduction of this wave's 16 rows into block accumulator
        int col = lane & 31, eo = lane >> 5;
#pragma unroll 1
        for (int e2 = eo; e2 < 16; e2 += 2) {
            int k = __shfl(ckey, e2);
            if (k >= 0)
                atomicAdd(&accH[k * 32 + col], ((const float*)(TbW + e2 * TPCH))[col]);
        }
    }
    __syncthreads();
    for (int idx = t; idx < VARS * PB * OUTD; idx += NT) {
        int key = idx >> 5, c = idx & 31;
        int v = key >> 3, lp = key & 7;     // PB == 8
        size_t rec = ((size_t)(v << 13) + p0 + lp) * RP;
        float val = accH[key * 32 + c] * invb[lp] + bf2f(f0b[rec + c]);
        f1b[rec + c] = f2bf(val);
    }
    if (t < VARS * PB) {
        int v = t >> 3, lp = t & 7;
        *(int*)(f1b + ((size_t)(v << 13) + p0 + lp) * RP + 32) = px2b[lp];
    }
}

// ---- kNN MLP + mean over K (LPTS=4 -> 512 blocks; weights from global) ----
__global__ __launch_bounds__(512, 8) void last_kernel(
    const unsigned short* __restrict__ f1b, const float* __restrict__ grid_out,
    const int* __restrict__ nbr_last,
    const unsigned short* __restrict__ wpack,
    const float* __restrict__ b0g, const float* __restrict__ b1g,
    const float* __restrict__ b2g,
    float* __restrict__ out)
{
    __shared__ __attribute__((aligned(16))) unsigned short Tb[NWAVES * 16 * TPCH];
    __shared__ __attribute__((aligned(16))) float bs[192];
    __shared__ __attribute__((aligned(16))) float accH[LPTS * VARS * 32];
    __shared__ int pxo2b[LPTS];

    const unsigned short* W0h = wpack;
    const unsigned short* W1h = wpack + W0SZ;
    const unsigned short* W2h = wpack + W0SZ + W1SZ;

    const int t = threadIdx.x;
    const int lane = t & 63, wave = t >> 6;
    const int lm = lane & 15, quad = lane >> 4;
    const int m0 = blockIdx.x * LPTS;

    for (int idx = t; idx < 192; idx += NT)
        bs[idx] = (idx < 80) ? b0g[idx] : (idx < 160 ? b1g[idx - 80] : b2g[idx - 160]);
    if (t < LPTS)
        pxo2b[t] = pk2(grid_out[2 * (m0 + t)], grid_out[2 * (m0 + t) + 1]);
    for (int idx = t; idx < LPTS * VARS * 32; idx += NT) accH[idx] = 0.0f;
    __syncthreads();
    unsigned short* TbW = Tb + (wave * 16) * TPCH;
    if (lane < 32)
        *(int4*)(TbW + (lane >> 1) * TPCH + 80 + (lane & 1) * 8) = make_int4(0, 0, 0, 0);

    const int Rb = LPTS * VARS * KLAST;   // 120
    const int nch = (Rb + 15) >> 4;       // 8
    unsigned short* Trow = TbW + lm * TPCH;

    for (int ch = wave; ch < nch; ch += NWAVES) {
        int myrow = (ch << 4) + lm;
        int ckey = -1; int4 cfeats = make_int4(0,0,0,0), cposf = make_int4(0,0,0,0);
        if (myrow < Rb) {
            int lp = myrow / 30, rr = myrow - lp * 30;
            int v = rr / KLAST, kk = rr - v * KLAST;
            int myj = nbr_last[(m0 + lp) * KLAST + kk];
            ckey = lp * VARS + v;
            const unsigned short* rec = f1b + ((size_t)(v << 13) + myj) * RP;
            cfeats = ((const int4*)rec)[quad];
            if (quad == 0) cposf = make_int4(*(const int*)(rec + 32), pxo2b[lp], 0, 0);
        }
        mlp_chunk(cfeats, cposf, Trow, W0h, W1h, W2h, bs, lm, quad);
        int col = lane & 31, eo = lane >> 5;
#pragma unroll 1
        for (int e2 = eo; e2 < 16; e2 += 2) {
            int k = __shfl(ckey, e2);
            if (k >= 0)
                atomicAdd(&accH[k * 32 + col], ((const float*)(TbW + e2 * TPCH))[col]);
        }
    }
    __syncthreads();
    if (t < LPTS * VARS * OUTD) {
        int key = t >> 5, c = t & 31;
        int lp = key / VARS, v = key - lp * VARS;
        out[((size_t)(m0 + lp) * VARS + v) * OUTD + c] = accH[key * 32 + c] * (1.0f / KLAST);
    }
}

extern "C" void kernel_launch(void* const* d_in, const int* in_sizes, int n_in,
                              void* d_out, int out_size, void* d_ws, size_t ws_size,
                              hipStream_t stream) {
    const float* inp      = (const float*)d_in[0];
    const float* grid_in  = (const float*)d_in[1];
    const float* grid_out = (const float*)d_in[2];
    const float* pW0 = (const float*)d_in[3];
    const float* pb0 = (const float*)d_in[4];
    const float* pW1 = (const float*)d_in[5];
    const float* pb1 = (const float*)d_in[6];
    const float* i0W0 = (const float*)d_in[7];
    const float* i0b0 = (const float*)d_in[8];
    const float* i0W1 = (const float*)d_in[9];
    const float* i0b1 = (const float*)d_in[10];
    const float* i0W2 = (const float*)d_in[11];
    const float* i0b2 = (const float*)d_in[12];
    const float* i1W0 = (const float*)d_in[13];
    const float* i1b0 = (const float*)d_in[14];
    const float* i1W1 = (const float*)d_in[15];
    const float* i1b1 = (const float*)d_in[16];
    const float* i1W2 = (const float*)d_in[17];
    const float* i1b2 = (const float*)d_in[18];
    const int* nbr_index  = (const int*)d_in[19];
    const int* nbr_counts = (const int*)d_in[21];
    const int* nbr_last   = (const int*)d_in[22];

    unsigned short* f0b = (unsigned short*)d_ws;                      // 3*8192*40 bf16
    unsigned short* f1b = f0b + (size_t)VARS * N_PTS * RP;            // 3*8192*40 bf16
    int* offsets = (int*)(f1b + (size_t)VARS * N_PTS * RP);           // N ints
    unsigned short* wpack0 = (unsigned short*)(offsets + N_PTS);      // 17408 bf16
    unsigned short* wpack1 = wpack0 + WPACK;                          // 17408 bf16

    proj_scan_kernel<<<771, 256, 0, stream>>>(inp, grid_in, pW0, pb0, pW1, pb1,
                                              f0b, nbr_counts, offsets,
                                              i0W0, i0W1, i0W2, wpack0,
                                              i1W0, i1W1, i1W2, wpack1);
    agg_kernel<<<N_PTS / PB, NT, 0, stream>>>(grid_in, f0b, nbr_index, offsets,
                                              nbr_counts, wpack0,
                                              i0b0, i0b1, i0b2, f1b);
    last_kernel<<<M_PTS / LPTS, NT, 0, stream>>>(f1b, grid_out, nbr_last, wpack1,
                                                 i1b0, i1b1, i1b2,
                                                 (float*)d_out);
}

// Round 17
// 305.497 us; speedup vs baseline: 1.1205x; 1.0069x over previous
//
#include <hip/hip_runtime.h>
#include <hip/hip_bf16.h>
#include <math.h>

#define N_PTS 8192
#define M_PTS 2048
#define KLAST 10
#define VARS 3
#define OUTD 32
#define D1 80
#define D2 80
#define PB 8          // points per agg block -> 1024 blocks, 4 blocks/CU
#define LPTS 4        // output points per last block -> 512 blocks
#define NT 512        // 8 waves per block
#define NWAVES 8
#define TPCH 104      // Tb row pitch in bf16 (208 B; stride-52 dwords -> 2-way banks)
#define W0P 72        // W0 K-pitch (K=64 used: feats 0..32, pos 32..36, pad ..64)
#define W1P 104       // W1/W2 K-pitch (K=80 padded to 96)
#define RP 32         // f0b/f1b record pitch in bf16 (64 B = ONE cache line)
#define W0SZ (D1 * W0P)              // 5760
#define W1SZ (D1 * W1P)              // 8320
#define W2SZ (OUTD * W1P)            // 3328
#define WPACK (W0SZ + W1SZ + W2SZ)   // 17408 bf16 elems per weight set

typedef float f4 __attribute__((ext_vector_type(4)));
typedef short bf16x8 __attribute__((ext_vector_type(8)));

// lean inf-safe tanh-gelu: gelu = x - x*rcp(exp2(x*(A+B*x^2))+1); err ~3e-4.
__device__ __forceinline__ float gelu_f(float x) {
    float x2 = x * x;
    float s = x * __builtin_fmaf(0.1029418f, x2, 2.3022083f);
    float u = __builtin_amdgcn_exp2f(s);
    float r = __builtin_amdgcn_rcpf(u + 1.0f);
    return __builtin_fmaf(-x, r, x);
}
__device__ __forceinline__ unsigned short f2bf(float x) {
    unsigned int u = __float_as_uint(x);
    u += 0x7FFF + ((u >> 16) & 1);
    return (unsigned short)(u >> 16);
}
__device__ __forceinline__ float bf2f(unsigned short h) {
    return __uint_as_float(((unsigned int)h) << 16);
}
// packed RNE f32x2 -> bf16x2 (v_cvt_pk_bf16_f32 on gfx950)
__device__ __forceinline__ int pk2(float a, float b) {
    __hip_bfloat162 h = __float22bfloat162_rn(float2{a, b});
    int r; __builtin_memcpy(&r, &h, 4); return r;
}

// One-time pack: single-bf16 weights transposed [col][k], K zero-padded, in
// the exact per-lane MFMA fragment layout. Consumers read fragments straight
// from global (coalesced 16B/lane, L1/L2-resident 35 KB set). W0 k-order
// REORDERED: k 0..31 <- W0g rows 4..35 (features), k 32..35 <- rows 0..3.
__device__ __forceinline__ void pack_weights(
    const float* __restrict__ W0g, const float* __restrict__ W1g,
    const float* __restrict__ W2g, unsigned short* __restrict__ wp, int t)
{
    for (int idx = t; idx < W0SZ; idx += 256) {
        int col = idx / W0P, k = idx - col * W0P;
        float w = (k < 32) ? W0g[(k + 4) * D1 + col]
                           : ((k < 36) ? W0g[(k - 32) * D1 + col] : 0.0f);
        wp[idx] = f2bf(w);
    }
    for (int idx = t; idx < W1SZ; idx += 256) {
        int col = idx / W1P, k = idx - col * W1P;
        wp[W0SZ + idx] = f2bf((k < D2) ? W1g[k * D1 + col] : 0.0f);
    }
    for (int idx = t; idx < W2SZ; idx += 256) {
        int col = idx / W1P, k = idx - col * W1P;
        wp[W0SZ + W1SZ + idx] = f2bf((k < D2) ? W2g[k * OUTD + col] : 0.0f);
    }
}

// Per-wave 16-row chunk MLP (R12-verified structure; weights from global).
// cb loops unroll-1 ON PURPOSE — every widened-live-set attempt spilled to
// scratch under the reg cap (R2/R3, R6/R7, R9, R14). Tripwire: FETCH/WRITE.
__device__ __forceinline__ void mlp_chunk(
    int4 featsi, int4 posfi, unsigned short* Trow,
    const unsigned short* __restrict__ W0h,
    const unsigned short* __restrict__ W1h,
    const unsigned short* __restrict__ W2h,
    const float* bs, int lm, int quad)
{
    bf16x8 b1f0 = *(bf16x8*)&featsi;
    bf16x8 b1f1 = *(bf16x8*)&posfi;
    // ---- L1: K=64 (feats+pos+pad) -> 80, gelu ----
#pragma unroll 1
    for (int cb = 0; cb < 5; ++cb) {
        f4 acc = *(const f4*)&bs[cb * 16 + quad * 4];
        bf16x8 a0 = *(const bf16x8*)&W0h[(cb * 16 + lm) * W0P + quad * 8];
        bf16x8 a1 = *(const bf16x8*)&W0h[(cb * 16 + lm) * W0P + 32 + quad * 8];
        acc = __builtin_amdgcn_mfma_f32_16x16x32_bf16(a0, b1f0, acc, 0, 0, 0);
        acc = __builtin_amdgcn_mfma_f32_16x16x32_bf16(a1, b1f1, acc, 0, 0, 0);
        *(int2*)&Trow[cb * 16 + quad * 4] =
            make_int2(pk2(gelu_f(acc.x), gelu_f(acc.y)),
                      pk2(gelu_f(acc.z), gelu_f(acc.w)));
    }
    // ---- L2: 80(pad 96) -> 80, gelu ----
    bf16x8 b2f[3];
    b2f[0] = *(const bf16x8*)&Trow[quad * 8];
    b2f[1] = *(const bf16x8*)&Trow[32 + quad * 8];
    b2f[2] = *(const bf16x8*)&Trow[64 + quad * 8];
#pragma unroll 1
    for (int cb = 0; cb < 5; ++cb) {
        f4 acc = *(const f4*)&bs[80 + cb * 16 + quad * 4];
        const unsigned short* wh = &W1h[(cb * 16 + lm) * W1P + quad * 8];
        bf16x8 h0 = *(const bf16x8*)&wh[0];
        bf16x8 h1 = *(const bf16x8*)&wh[32];
        bf16x8 h2 = *(const bf16x8*)&wh[64];
        acc = __builtin_amdgcn_mfma_f32_16x16x32_bf16(h0, b2f[0], acc, 0, 0, 0);
        acc = __builtin_amdgcn_mfma_f32_16x16x32_bf16(h1, b2f[1], acc, 0, 0, 0);
        acc = __builtin_amdgcn_mfma_f32_16x16x32_bf16(h2, b2f[2], acc, 0, 0, 0);
        *(int2*)&Trow[cb * 16 + quad * 4] =
            make_int2(pk2(gelu_f(acc.x), gelu_f(acc.y)),
                      pk2(gelu_f(acc.z), gelu_f(acc.w)));
    }
    // ---- L3: 80(pad 96) -> 32, fp32 out at Trow floats [0..32) ----
    bf16x8 b3f[3];
    b3f[0] = *(const bf16x8*)&Trow[quad * 8];
    b3f[1] = *(const bf16x8*)&Trow[32 + quad * 8];
    b3f[2] = *(const bf16x8*)&Trow[64 + quad * 8];
    float* po = (float*)Trow;
#pragma unroll 1
    for (int cb = 0; cb < 2; ++cb) {
        f4 acc = *(const f4*)&bs[160 + cb * 16 + quad * 4];
        const unsigned short* wh = &W2h[(cb * 16 + lm) * W1P + quad * 8];
        bf16x8 h0 = *(const bf16x8*)&wh[0];
        bf16x8 h1 = *(const bf16x8*)&wh[32];
        bf16x8 h2 = *(const bf16x8*)&wh[64];
        acc = __builtin_amdgcn_mfma_f32_16x16x32_bf16(h0, b3f[0], acc, 0, 0, 0);
        acc = __builtin_amdgcn_mfma_f32_16x16x32_bf16(h1, b3f[1], acc, 0, 0, 0);
        acc = __builtin_amdgcn_mfma_f32_16x16x32_bf16(h2, b3f[2], acc, 0, 0, 0);
        *(f4*)&po[cb * 16 + quad * 4] = acc;
    }
}

// ---- merged projection + scan + weight-pack ----
__global__ __launch_bounds__(256) void proj_scan_kernel(
    const float* __restrict__ inp, const float* __restrict__ grid_in,
    const float* __restrict__ W0, const float* __restrict__ b0,
    const float* __restrict__ W1, const float* __restrict__ b1,
    unsigned short* __restrict__ f0b, int* __restrict__ posb,
    const int* __restrict__ counts, int* __restrict__ offsets,
    const float* __restrict__ i0W0, const float* __restrict__ i0W1,
    const float* __restrict__ i0W2, unsigned short* __restrict__ wpack0,
    const float* __restrict__ i1W0, const float* __restrict__ i1W1,
    const float* __restrict__ i1W2, unsigned short* __restrict__ wpack1)
{
    const int t = threadIdx.x;
    if (blockIdx.x == 769) { pack_weights(i0W0, i0W1, i0W2, wpack0, t); return; }
    if (blockIdx.x == 770) { pack_weights(i1W0, i1W1, i1W2, wpack1, t); return; }
    if (blockIdx.x == 768) {
        __shared__ int ws2[4], wx2[4];
        const int lane = t & 63, wave = t >> 6;
        int4 a[8];
#pragma unroll
        for (int i = 0; i < 8; ++i) a[i] = ((const int4*)counts)[t * 8 + i];
        int s = 0;
#pragma unroll
        for (int i = 0; i < 8; ++i) s += a[i].x + a[i].y + a[i].z + a[i].w;
        int x = s;
#pragma unroll
        for (int d = 1; d < 64; d <<= 1) {
            int y = __shfl_up(x, d);
            if (lane >= d) x += y;
        }
        if (lane == 63) ws2[wave] = x;
        __syncthreads();
        if (t == 0) {
            wx2[0] = 0;
            wx2[1] = ws2[0];
            wx2[2] = ws2[0] + ws2[1];
            wx2[3] = ws2[0] + ws2[1] + ws2[2];
        }
        __syncthreads();
        int base = wx2[wave] + (x - s);
#pragma unroll
        for (int i = 0; i < 8; ++i) {
            int4 c = a[i];
            int4 o;
            o.x = base; base += c.x;
            o.y = base; base += c.y;
            o.z = base; base += c.z;
            o.w = base; base += c.w;
            ((int4*)offsets)[t * 8 + i] = o;
        }
        return;
    }
    __shared__ float W0s[8 * 64];
    __shared__ float W1s[64 * OUTD];
    __shared__ float xs[32 * 8];
    __shared__ float H[32 * 64];
    const int r0 = blockIdx.x * 32;
    for (int idx = t; idx < 512; idx += 256) W0s[idx] = W0[idx];
    for (int idx = t; idx < 64 * OUTD; idx += 256) W1s[idx] = W1[idx];
    xs[t] = inp[r0 * 8 + t];
    if (t < 32) {
        int row = r0 + t, n = row / 3;
        posb[n] = pk2(grid_in[2 * n], grid_in[2 * n + 1]);  // dup writes benign
    }
    __syncthreads();
#pragma unroll 1
    for (int p = 0; p < 8; ++p) {
        int o = t + 256 * p, r = o >> 6, col = o & 63;
        float s = b0[col];
#pragma unroll
        for (int k = 0; k < 8; ++k) s += xs[r * 8 + k] * W0s[k * 64 + col];
        H[o] = gelu_f(s);
    }
    __syncthreads();
#pragma unroll 1
    for (int p = 0; p < 4; ++p) {
        int o = t + 256 * p, r = o >> 5, c = o & 31;
        float s = b1[c];
#pragma unroll 8
        for (int k = 0; k < 64; ++k) s += H[r * 64 + k] * W1s[k * OUTD + c];
        int row = r0 + r;
        int n = row / 3, v = row - n * 3;
        f0b[((size_t)(v << 13) + n) * RP + c] = f2bf(s);
    }
}

// ---- edge MLP + owner-computes segment mean ----
// 8 waves x 512 thr, PB=8 -> 1024 blocks, 4 blocks/CU = 32 waves/CU.
// Records are 64 B line-aligned: each gather touches exactly one cache line.
__global__ __launch_bounds__(512, 8) void agg_kernel(
    const float* __restrict__ grid_in, const unsigned short* __restrict__ f0b,
    const int* __restrict__ posb,
    const int* __restrict__ nbr_index, const int* __restrict__ offsets,
    const int* __restrict__ counts,
    const unsigned short* __restrict__ wpack,
    const float* __restrict__ b0g, const float* __restrict__ b1g,
    const float* __restrict__ b2g,
    unsigned short* __restrict__ f1b)
{
    __shared__ __attribute__((aligned(16))) unsigned short Tb[NWAVES * 16 * TPCH];
    __shared__ __attribute__((aligned(16))) float bs[192];
    __shared__ __attribute__((aligned(16))) float accH[VARS * PB * 32];
    __shared__ int offs[PB + 1];
    __shared__ int px2b[PB];
    __shared__ float invb[PB];

    const unsigned short* W0h = wpack;
    const unsigned short* W1h = wpack + W0SZ;
    const unsigned short* W2h = wpack + W0SZ + W1SZ;

    const int t = threadIdx.x;
    const int lane = t & 63, wave = t >> 6;
    const int lm = lane & 15, quad = lane >> 4;
    const int p0 = blockIdx.x * PB;

    for (int idx = t; idx < 192; idx += NT)
        bs[idx] = (idx < 80) ? b0g[idx] : (idx < 160 ? b1g[idx - 80] : b2g[idx - 160]);
    if (t < PB) {
        offs[t] = offsets[p0 + t];
        int c = counts[p0 + t];
        invb[t] = 1.0f / (float)(c > 1 ? c : 1);
        px2b[t] = pk2(grid_in[2 * (p0 + t)], grid_in[2 * (p0 + t) + 1]);
    }
    if (t == PB) offs[PB] = offsets[p0 + PB - 1] + counts[p0 + PB - 1];
    for (int idx = t; idx < VARS * PB * 32; idx += NT) accH[idx] = 0.0f;
    __syncthreads();

    // zero persistent pad [80..96) of this wave's 16 rows (never rewritten)
    unsigned short* TbW = Tb + (wave * 16) * TPCH;
    if (lane < 32)
        *(int4*)(TbW + (lane >> 1) * TPCH + 80 + (lane & 1) * 8) = make_int4(0, 0, 0, 0);

    const int e0 = offs[0];
    const int cntT = offs[PB] - e0;
    const int Rb = VARS * cntT;
    const int nch = (Rb + 15) >> 4;

    unsigned short* Trow = TbW + lm * TPCH;

    // prefetch state for chunk ch
    int pkey; int4 pfeats, pposf;
    {
        int myrow = (wave << 4) + lm;
        pkey = -1; pfeats = make_int4(0,0,0,0); pposf = make_int4(0,0,0,0);
        if (myrow < Rb) {
            int myv = (myrow >= 2 * cntT) ? 2 : ((myrow >= cntT) ? 1 : 0);
            int e = e0 + myrow - myv * cntT;
            int myj = nbr_index[e];
            int lp = 0;
#pragma unroll
            for (int l = 1; l < PB; ++l) lp += (e >= offs[l]);
            pkey = myv * PB + lp;
            pfeats = ((const int4*)(f0b + ((size_t)(myv << 13) + myj) * RP))[quad];
            if (quad == 0) pposf = make_int4(posb[myj], px2b[lp], 0, 0);
        }
    }

    for (int ch = wave; ch < nch; ch += NWAVES) {
        int ckey = pkey; int4 cfeats = pfeats, cposf = pposf;
        // issue next chunk's gather before the MLP (latency hides behind MFMA)
        int nc = ch + NWAVES;
        pkey = -1; pfeats = make_int4(0,0,0,0); pposf = make_int4(0,0,0,0);
        if (nc < nch) {
            int myrow = (nc << 4) + lm;
            if (myrow < Rb) {
                int myv = (myrow >= 2 * cntT) ? 2 : ((myrow >= cntT) ? 1 : 0);
                int e = e0 + myrow - myv * cntT;
                int myj = nbr_index[e];
                int lp = 0;
#pragma unroll
                for (int l = 1; l < PB; ++l) lp += (e >= offs[l]);
                pkey = myv * PB + lp;
                pfeats = ((const int4*)(f0b + ((size_t)(myv << 13) + myj) * RP))[quad];
                if (quad == 0) pposf = make_int4(posb[myj], px2b[lp], 0, 0);
            }
        }
        if (ckey < 0) { cfeats = make_int4(0,0,0,0); cposf = make_int4(0,0,0,0); }
        mlp_chunk(cfeats, cposf, Trow, W0h, W1h, W2h, bs, lm, quad);
        // keyed reduction of this wave's 16 rows into block accumulator
        int col = lane & 31, eo = lane >> 5;
#pragma unroll 1
        for (int e2 = eo; e2 < 16; e2 += 2) {
            int k = __shfl(ckey, e2);
            if (k >= 0)
                atomicAdd(&accH[k * 32 + col], ((const float*)(TbW + e2 * TPCH))[col]);
        }
    }
    __syncthreads();
    for (int idx = t; idx < VARS * PB * OUTD; idx += NT) {
        int key = idx >> 5, c = idx & 31;
        int v = key >> 3, lp = key & 7;     // PB == 8
        size_t rec = ((size_t)(v << 13) + p0 + lp) * RP;
        float val = accH[key * 32 + c] * invb[lp] + bf2f(f0b[rec + c]);
        f1b[rec + c] = f2bf(val);
    }
}

// ---- kNN MLP + mean over K (LPTS=4 -> 512 blocks; weights from global) ----
__global__ __launch_bounds__(512, 8) void last_kernel(
    const unsigned short* __restrict__ f1b, const int* __restrict__ posb,
    const float* __restrict__ grid_out,
    const int* __restrict__ nbr_last,
    const unsigned short* __restrict__ wpack,
    const float* __restrict__ b0g, const float* __restrict__ b1g,
    const float* __restrict__ b2g,
    float* __restrict__ out)
{
    __shared__ __attribute__((aligned(16))) unsigned short Tb[NWAVES * 16 * TPCH];
    __shared__ __attribute__((aligned(16))) float bs[192];
    __shared__ __attribute__((aligned(16))) float accH[LPTS * VARS * 32];
    __shared__ int pxo2b[LPTS];

    const unsigned short* W0h = wpack;
    const unsigned short* W1h = wpack + W0SZ;
    const unsigned short* W2h = wpack + W0SZ + W1SZ;

    const int t = threadIdx.x;
    const int lane = t & 63, wave = t >> 6;
    const int lm = lane & 15, quad = lane >> 4;
    const int m0 = blockIdx.x * LPTS;

    for (int idx = t; idx < 192; idx += NT)
        bs[idx] = (idx < 80) ? b0g[idx] : (idx < 160 ? b1g[idx - 80] : b2g[idx - 160]);
    if (t < LPTS)
        pxo2b[t] = pk2(grid_out[2 * (m0 + t)], grid_out[2 * (m0 + t) + 1]);
    for (int idx = t; idx < LPTS * VARS * 32; idx += NT) accH[idx] = 0.0f;
    __syncthreads();
    unsigned short* TbW = Tb + (wave * 16) * TPCH;
    if (lane < 32)
        *(int4*)(TbW + (lane >> 1) * TPCH + 80 + (lane & 1) * 8) = make_int4(0, 0, 0, 0);

    const int Rb = LPTS * VARS * KLAST;   // 120
    const int nch = (Rb + 15) >> 4;       // 8
    unsigned short* Trow = TbW + lm * TPCH;

    for (int ch = wave; ch < nch; ch += NWAVES) {
        int myrow = (ch << 4) + lm;
        int ckey = -1; int4 cfeats = make_int4(0,0,0,0), cposf = make_int4(0,0,0,0);
        if (myrow < Rb) {
            int lp = myrow / 30, rr = myrow - lp * 30;
            int v = rr / KLAST, kk = rr - v * KLAST;
            int myj = nbr_last[(m0 + lp) * KLAST + kk];
            ckey = lp * VARS + v;
            cfeats = ((const int4*)(f1b + ((size_t)(v << 13) + myj) * RP))[quad];
            if (quad == 0) cposf = make_int4(posb[myj], pxo2b[lp], 0, 0);
        }
        mlp_chunk(cfeats, cposf, Trow, W0h, W1h, W2h, bs, lm, quad);
        int col = lane & 31, eo = lane >> 5;
#pragma unroll 1
        for (int e2 = eo; e2 < 16; e2 += 2) {
            int k = __shfl(ckey, e2);
            if (k >= 0)
                atomicAdd(&accH[k * 32 + col], ((const float*)(TbW + e2 * TPCH))[col]);
        }
    }
    __syncthreads();
    if (t < LPTS * VARS * OUTD) {
        int key = t >> 5, c = t & 31;
        int lp = key / VARS, v = key - lp * VARS;
        out[((size_t)(m0 + lp) * VARS + v) * OUTD + c] = accH[key * 32 + c] * (1.0f / KLAST);
    }
}

extern "C" void kernel_launch(void* const* d_in, const int* in_sizes, int n_in,
                              void* d_out, int out_size, void* d_ws, size_t ws_size,
                              hipStream_t stream) {
    const float* inp      = (const float*)d_in[0];
    const float* grid_in  = (const float*)d_in[1];
    const float* grid_out = (const float*)d_in[2];
    const float* pW0 = (const float*)d_in[3];
    const float* pb0 = (const float*)d_in[4];
    const float* pW1 = (const float*)d_in[5];
    const float* pb1 = (const float*)d_in[6];
    const float* i0W0 = (const float*)d_in[7];
    const float* i0b0 = (const float*)d_in[8];
    const float* i0W1 = (const float*)d_in[9];
    const float* i0b1 = (const float*)d_in[10];
    const float* i0W2 = (const float*)d_in[11];
    const float* i0b2 = (const float*)d_in[12];
    const float* i1W0 = (const float*)d_in[13];
    const float* i1b0 = (const float*)d_in[14];
    const float* i1W1 = (const float*)d_in[15];
    const float* i1b1 = (const float*)d_in[16];
    const float* i1W2 = (const float*)d_in[17];
    const float* i1b2 = (const float*)d_in[18];
    const int* nbr_index  = (const int*)d_in[19];
    const int* nbr_counts = (const int*)d_in[21];
    const int* nbr_last   = (const int*)d_in[22];

    unsigned short* f0b = (unsigned short*)d_ws;                      // 3*8192*32 bf16
    unsigned short* f1b = f0b + (size_t)VARS * N_PTS * RP;            // 3*8192*32 bf16
    int* offsets = (int*)(f1b + (size_t)VARS * N_PTS * RP);           // N ints
    int* posb    = offsets + N_PTS;                                   // N ints (bf16x2)
    unsigned short* wpack0 = (unsigned short*)(posb + N_PTS);         // 17408 bf16
    unsigned short* wpack1 = wpack0 + WPACK;                          // 17408 bf16

    proj_scan_kernel<<<771, 256, 0, stream>>>(inp, grid_in, pW0, pb0, pW1, pb1,
                                              f0b, posb, nbr_counts, offsets,
                                              i0W0, i0W1, i0W2, wpack0,
                                              i1W0, i1W1, i1W2, wpack1);
    agg_kernel<<<N_PTS / PB, NT, 0, stream>>>(grid_in, f0b, posb, nbr_index, offsets,
                                              nbr_counts, wpack0,
                                              i0b0, i0b1, i0b2, f1b);
    last_kernel<<<M_PTS / LPTS, NT, 0, stream>>>(f1b, posb, grid_out, nbr_last, wpack1,
                                                 i1b0, i1b1, i1b2,
                                                 (float*)d_out);
}